// Round 7
// baseline (239.744 us; speedup 1.0000x reference)
//
#include <hip/hip_runtime.h>

typedef unsigned short u16;
typedef __attribute__((ext_vector_type(8))) short bfrag;   // 8 x bf16
typedef __attribute__((ext_vector_type(4))) float f32x4;

#define SROW 1032   // padded LDS row stride (bf16 elems): 2064 B
#define ACCW 36     // sh_acc row stride in f32

__device__ __forceinline__ u16 f2bf(float x) {
    unsigned int v = __float_as_uint(x);
    return (u16)((v + 0x7FFFu + ((v >> 16) & 1u)) >> 16);   // RNE
}

// tanh(x) = 1 - 2/(e^{2x}+1): 5-op dependent chain, inf-safe.
__device__ __forceinline__ float fast_tanh(float x) {
    float e = __builtin_amdgcn_exp2f(x * 2.885390081777927f);
    return __builtin_fmaf(-2.0f, __builtin_amdgcn_rcpf(e + 1.0f), 1.0f);
}

// ---------------- prologue: bf16 conversions + 32x32 diag-block transpose ----------------
__global__ void ren_prologue(const float* __restrict__ Bs, const float* __restrict__ Bw,
                             const float* __restrict__ Ds, const float* __restrict__ Dw,
                             u16* __restrict__ bs16, u16* __restrict__ bw16,
                             u16* __restrict__ ds16, u16* __restrict__ dw16,
                             float* __restrict__ diagT)
{
    const int g = blockIdx.x * 256 + threadIdx.x;
    if (g < 262144) {
        const int idx = g * 4;
        const int i = idx >> 10, j = idx & 1023;
        const float4 v = *reinterpret_cast<const float4*>(Bs + idx);
        u16 o[4];
        o[0] = (j + 0 < i) ? f2bf(v.x) : (u16)0;
        o[1] = (j + 1 < i) ? f2bf(v.y) : (u16)0;
        o[2] = (j + 2 < i) ? f2bf(v.z) : (u16)0;
        o[3] = (j + 3 < i) ? f2bf(v.w) : (u16)0;
        *reinterpret_cast<uint2*>(bs16 + idx) = *reinterpret_cast<const uint2*>(o);
    } else if (g < 294912) {
        const int idx = (g - 262144) * 4;
        const float4 v = *reinterpret_cast<const float4*>(Bw + idx);
        u16 o[4] = { f2bf(v.x), f2bf(v.y), f2bf(v.z), f2bf(v.w) };
        *reinterpret_cast<uint2*>(bw16 + idx) = *reinterpret_cast<const uint2*>(o);
    } else if (g < 327680) {
        const int idx = (g - 294912) * 4;
        const float4 v = *reinterpret_cast<const float4*>(Ds + idx);
        u16 o[4] = { f2bf(v.x), f2bf(v.y), f2bf(v.z), f2bf(v.w) };
        *reinterpret_cast<uint2*>(ds16 + idx) = *reinterpret_cast<const uint2*>(o);
    } else if (g < 331776) {
        const int idx = (g - 327680) * 4;
        const float4 v = *reinterpret_cast<const float4*>(Dw + idx);
        u16 o[4] = { f2bf(v.x), f2bf(v.y), f2bf(v.z), f2bf(v.w) };
        *reinterpret_cast<uint2*>(dw16 + idx) = *reinterpret_cast<const uint2*>(o);
    } else if (g < 339968) {
        const int lin0 = (g - 331776) * 4;
        #pragma unroll
        for (int t = 0; t < 4; ++t) {
            const int l = lin0 + t;
            const int bb = l >> 10, rem = l & 1023, i = rem >> 5, j = rem & 31;
            // diagT[b][i][j] = Bs[32b+j, 32b+i] for j>i (weight from unit i to unit j)
            diagT[l] = (j > i) ? Bs[(size_t)(bb * 32 + j) * 1024 + (bb * 32 + i)] : 0.0f;
        }
    }
}

// ---------------- main: pipelined triangular recurrence ----------------
// 256 wgs x 320 threads (5 waves), 32 batch rows per wg -> 1 wg/CU.
// Waves 0-3: GEMM producers, 2x2 tile (mt=wave>>1 rows, nt=wave&1 cols).
// Wave 4: serial consumer, lane = batch row (lanes 0-31), with a
// sched_barrier-pinned 2-step-ahead LDS weight prefetch.
__global__ __launch_bounds__(320) void ren_main(
    const float* __restrict__ u,
    const u16* __restrict__ bs16, const u16* __restrict__ bw16,
    const u16* __restrict__ ds16, const u16* __restrict__ dw16,
    const float* __restrict__ diagT,
    float* __restrict__ out)
{
    __shared__ __align__(16) u16   sh_S[32 * SROW];    // s history bf16 [32][1024+pad]
    __shared__ __align__(16) float sh_acc[32 * ACCW];  // pre-activation tile [32][36]
    __shared__ __align__(16) float sh_dT[2][1024];     // dbuf diag block f32 [32][32]

    const int tid  = threadIdx.x;
    const int wave = tid >> 6;
    const int lane = tid & 63;
    const int mt   = (wave >> 1) & 1;      // row-tile for GEMM waves
    const int nt   = wave & 1;             // col-tile for GEMM waves
    const int lr   = lane & 15;
    const int lk8  = (lane >> 4) << 3;
    const int row0 = blockIdx.x << 5;      // 32 batch rows per wg

    bfrag fu[4];                           // u A-frags (GEMM waves only)
    f32x4 acc;                             // next-block partial accumulator

    if (wave < 4) {
        const float* up = u + (size_t)(row0 + mt * 16 + lr) * 128 + lk8;
        #pragma unroll
        for (int kk = 0; kk < 4; ++kk) {
            float4 a = *reinterpret_cast<const float4*>(up + kk * 32);
            float4 c = *reinterpret_cast<const float4*>(up + kk * 32 + 4);
            bfrag f;
            f[0] = (short)f2bf(a.x); f[1] = (short)f2bf(a.y);
            f[2] = (short)f2bf(a.z); f[3] = (short)f2bf(a.w);
            f[4] = (short)f2bf(c.x); f[5] = (short)f2bf(c.y);
            f[6] = (short)f2bf(c.z); f[7] = (short)f2bf(c.w);
            fu[kk] = f;
        }
        // stage dT block 0 (1024 f32 by threads 0-127)
        if (tid < 128) {
            const float4* g = reinterpret_cast<const float4*>(diagT);
            float4 a = g[2 * tid], c = g[2 * tid + 1];
            *reinterpret_cast<float4*>(&sh_dT[0][tid * 8])     = a;
            *reinterpret_cast<float4*>(&sh_dT[0][tid * 8 + 4]) = c;
        }
        // block 0 pre-activations = Bu only (each wave: its 16x16 quadrant)
        acc = (f32x4){0.f, 0.f, 0.f, 0.f};
        const u16* p0 = bw16 + (size_t)((nt << 4) + lr) * 128 + lk8;
        #pragma unroll
        for (int kk = 0; kk < 4; ++kk)
            acc = __builtin_amdgcn_mfma_f32_16x16x32_bf16(fu[kk], *reinterpret_cast<const bfrag*>(p0 + kk * 32), acc, 0, 0, 0);
        const int m = (mt << 4) + ((lane >> 4) << 2);
        #pragma unroll
        for (int rr = 0; rr < 4; ++rr)
            sh_acc[(m + rr) * ACCW + (nt << 4) + lr] = acc[rr];
    }
    __syncthreads();

    for (int b = 0; b < 32; ++b) {
        bfrag bfin;                        // finish B-frag, preloaded pre-barrier
        const int nb = b + 1;

        if (wave == 4) {
            // ---------- serial consumer: 32 steps for block b ----------
            if (lane < 32) {
                const float4* dT4 = reinterpret_cast<const float4*>(&sh_dT[b & 1][0]);
                float4 wreg[3][8];
                #pragma unroll
                for (int q = 0; q < 8; ++q) wreg[0][q] = dT4[q];       // step 0
                #pragma unroll
                for (int q = 0; q < 8; ++q) wreg[1][q] = dT4[8 + q];   // step 1
                float part[32];
                const float* accr = sh_acc + lane * ACCW;
                #pragma unroll
                for (int q = 0; q < 8; ++q) {
                    float4 v = reinterpret_cast<const float4*>(accr)[q];
                    part[4*q+0] = v.x; part[4*q+1] = v.y; part[4*q+2] = v.z; part[4*q+3] = v.w;
                }
                __builtin_amdgcn_sched_barrier(0);
                u16* srow = sh_S + lane * SROW + (b << 5);
                u16 sv[8];
                #pragma unroll
                for (int i = 0; i < 32; ++i) {
                    // region A: prefetch step i+2's weight quads (pinned here)
                    if (i + 2 < 32) {
                        #pragma unroll
                        for (int q = (i + 3) >> 2; q < 8; ++q)
                            wreg[(i + 2) % 3][q] = dT4[((i + 2) << 3) + q];
                    }
                    __builtin_amdgcn_sched_barrier(0);
                    // region B: compute step i from step-i regs (loaded 2 steps ago)
                    float s = fast_tanh(part[i]);
                    sv[i & 7] = (u16)((__float_as_uint(s) + 0x8000u) >> 16);
                    if ((i & 7) == 7) {   // flush 8 packed bf16 to LDS
                        uint4 pk;
                        pk.x = (unsigned)sv[0] | ((unsigned)sv[1] << 16);
                        pk.y = (unsigned)sv[2] | ((unsigned)sv[3] << 16);
                        pk.z = (unsigned)sv[4] | ((unsigned)sv[5] << 16);
                        pk.w = (unsigned)sv[6] | ((unsigned)sv[7] << 16);
                        *reinterpret_cast<uint4*>(srow + ((i >> 3) << 3)) = pk;
                    }
                    #pragma unroll
                    for (int q = (i + 1) >> 2; q < 8; ++q) {
                        float4 w = wreg[i % 3][q];   // zero-padded for j<=i
                        part[4*q+0] = __builtin_fmaf(w.x, s, part[4*q+0]);
                        part[4*q+1] = __builtin_fmaf(w.y, s, part[4*q+1]);
                        part[4*q+2] = __builtin_fmaf(w.z, s, part[4*q+2]);
                        part[4*q+3] = __builtin_fmaf(w.w, s, part[4*q+3]);
                    }
                    __builtin_amdgcn_sched_barrier(0);
                }
            }
        } else if (b < 31) {
            // ---------- GEMM producers: partial for block b+1 (kc < b) ----------
            float4 st0, st1;
            const bool stager = (tid < 128);
            if (stager) {
                const float4* g = reinterpret_cast<const float4*>(diagT + (nb << 10));
                st0 = g[2 * tid]; st1 = g[2 * tid + 1];
            }
            const int ng = (nb << 5) + (nt << 4) + lr;     // global hid unit
            bfin = *reinterpret_cast<const bfrag*>(bs16 + (size_t)ng * 1024 + (b << 5) + lk8);

            acc = (f32x4){0.f, 0.f, 0.f, 0.f};
            const u16* p0 = bw16 + (size_t)ng * 128 + lk8;
            #pragma unroll
            for (int kk = 0; kk < 4; ++kk)
                acc = __builtin_amdgcn_mfma_f32_16x16x32_bf16(fu[kk], *reinterpret_cast<const bfrag*>(p0 + kk * 32), acc, 0, 0, 0);

            const u16* bsp = bs16 + (size_t)ng * 1024 + lk8;
            const u16* ssp = sh_S + ((mt << 4) + lr) * SROW + lk8;
            #pragma unroll 8
            for (int kc = 0; kc < b; ++kc) {
                bfrag af = *reinterpret_cast<const bfrag*>(ssp + (kc << 5));
                acc = __builtin_amdgcn_mfma_f32_16x16x32_bf16(af, *reinterpret_cast<const bfrag*>(bsp + (kc << 5)), acc, 0, 0, 0);
            }
            if (stager) {
                *reinterpret_cast<float4*>(&sh_dT[nb & 1][tid * 8])     = st0;
                *reinterpret_cast<float4*>(&sh_dT[nb & 1][tid * 8 + 4]) = st1;
            }
        }
        __syncthreads();   // s_b visible; partials done

        if (wave < 4 && b < 31) {
            // ---------- finish block b+1 with the fresh s_b k-slice ----------
            const u16* ssp = sh_S + ((mt << 4) + lr) * SROW + lk8;
            bfrag af = *reinterpret_cast<const bfrag*>(ssp + (b << 5));
            acc = __builtin_amdgcn_mfma_f32_16x16x32_bf16(af, bfin, acc, 0, 0, 0);
            const int m = (mt << 4) + ((lane >> 4) << 2);
            #pragma unroll
            for (int rr = 0; rr < 4; ++rr)
                sh_acc[(m + rr) * ACCW + (nt << 4) + lr] = acc[rr];
        }
        __syncthreads();   // sh_acc ready for serial(b+1)
    }

    if (wave >= 4) return;

    // ---------------- epilogue: y = s @ Ds^T + u @ D^T ----------------
    // wave (mt,nt): rows mt*16.., cols (nt*4+t)*16.. for t=0..3
    f32x4 ey[4];
    #pragma unroll
    for (int t = 0; t < 4; ++t) ey[t] = (f32x4){0.f, 0.f, 0.f, 0.f};

    const u16* ssp = sh_S + ((mt << 4) + lr) * SROW + lk8;
    #pragma unroll 4
    for (int kc = 0; kc < 32; ++kc) {
        bfrag af = *reinterpret_cast<const bfrag*>(ssp + (kc << 5));
        #pragma unroll
        for (int t = 0; t < 4; ++t) {
            const int n = ((nt << 2) + t) * 16 + lr;
            bfrag bf = *reinterpret_cast<const bfrag*>(ds16 + (size_t)n * 1024 + (kc << 5) + lk8);
            ey[t] = __builtin_amdgcn_mfma_f32_16x16x32_bf16(af, bf, ey[t], 0, 0, 0);
        }
    }
    #pragma unroll
    for (int kk = 0; kk < 4; ++kk) {
        #pragma unroll
        for (int t = 0; t < 4; ++t) {
            const int n = ((nt << 2) + t) * 16 + lr;
            bfrag bf = *reinterpret_cast<const bfrag*>(dw16 + n * 128 + (kk << 5) + lk8);
            ey[t] = __builtin_amdgcn_mfma_f32_16x16x32_bf16(fu[kk], bf, ey[t], 0, 0, 0);
        }
    }
    {
        const int mbase = row0 + (mt << 4) + ((lane >> 4) << 2);
        #pragma unroll
        for (int t = 0; t < 4; ++t) {
            const int n = ((nt << 2) + t) * 16 + lr;
            #pragma unroll
            for (int rr = 0; rr < 4; ++rr)
                out[(size_t)(mbase + rr) * 128 + n] = ey[t][rr];
        }
    }
}

extern "C" void kernel_launch(void* const* d_in, const int* in_sizes, int n_in,
                              void* d_out, int out_size, void* d_ws, size_t ws_size,
                              hipStream_t stream)
{
    const float* u  = (const float*)d_in[0];   // [8192,128]
    const float* Bw = (const float*)d_in[1];   // [1024,128]
    const float* Bs = (const float*)d_in[2];   // [1024,1024]
    const float* Ds = (const float*)d_in[3];   // [128,1024]
    const float* Dw = (const float*)d_in[4];   // [128,128]
    float* out = (float*)d_out;

    u16* bs16 = (u16*)d_ws;                    // 1024*1024 bf16
    u16* bw16 = bs16 + 1024 * 1024;            // 1024*128
    u16* ds16 = bw16 + 1024 * 128;             // 128*1024
    u16* dw16 = ds16 + 128 * 1024;             // 128*128
    float* diagT = (float*)(dw16 + 128 * 128); // 32 blocks x 32x32 f32, transposed

    ren_prologue<<<1328, 256, 0, stream>>>(Bs, Bw, Ds, Dw, bs16, bw16, ds16, dw16, diagT);
    ren_main<<<256, 320, 0, stream>>>(u, bs16, bw16, ds16, dw16, diagT, out);
}

// Round 9
// 166.670 us; speedup vs baseline: 1.4384x; 1.4384x over previous
//
#include <hip/hip_runtime.h>

typedef unsigned short u16;
typedef unsigned int u32;
typedef __attribute__((ext_vector_type(8))) short bfrag;   // 8 x bf16
typedef __attribute__((ext_vector_type(4))) float f32x4;

#define SROW 1032   // padded LDS row stride (bf16 elems): 2064 B
#define ACCW 36     // sh_acc row stride in f32

__device__ __forceinline__ u16 f2bf(float x) {
    unsigned int v = __float_as_uint(x);
    return (u16)((v + 0x7FFFu + ((v >> 16) & 1u)) >> 16);   // RNE
}

// tanh(x) = 1 - 2/(e^{2x}+1): 5-op dependent chain, inf-safe.
__device__ __forceinline__ float fast_tanh(float x) {
    float e = __builtin_amdgcn_exp2f(x * 2.885390081777927f);
    return __builtin_fmaf(-2.0f, __builtin_amdgcn_rcpf(e + 1.0f), 1.0f);
}

// ---------------- prologue: bf16 conversions + 32x32 diag-block transpose ----------------
__global__ void ren_prologue(const float* __restrict__ Bs, const float* __restrict__ Bw,
                             const float* __restrict__ Ds, const float* __restrict__ Dw,
                             u16* __restrict__ bs16, u16* __restrict__ bw16,
                             u16* __restrict__ ds16, u16* __restrict__ dw16,
                             float* __restrict__ diagT)
{
    const int g = blockIdx.x * 256 + threadIdx.x;
    if (g < 262144) {
        const int idx = g * 4;
        const int i = idx >> 10, j = idx & 1023;
        const float4 v = *reinterpret_cast<const float4*>(Bs + idx);
        u16 o[4];
        o[0] = (j + 0 < i) ? f2bf(v.x) : (u16)0;
        o[1] = (j + 1 < i) ? f2bf(v.y) : (u16)0;
        o[2] = (j + 2 < i) ? f2bf(v.z) : (u16)0;
        o[3] = (j + 3 < i) ? f2bf(v.w) : (u16)0;
        *reinterpret_cast<uint2*>(bs16 + idx) = *reinterpret_cast<const uint2*>(o);
    } else if (g < 294912) {
        const int idx = (g - 262144) * 4;
        const float4 v = *reinterpret_cast<const float4*>(Bw + idx);
        u16 o[4] = { f2bf(v.x), f2bf(v.y), f2bf(v.z), f2bf(v.w) };
        *reinterpret_cast<uint2*>(bw16 + idx) = *reinterpret_cast<const uint2*>(o);
    } else if (g < 327680) {
        const int idx = (g - 294912) * 4;
        const float4 v = *reinterpret_cast<const float4*>(Ds + idx);
        u16 o[4] = { f2bf(v.x), f2bf(v.y), f2bf(v.z), f2bf(v.w) };
        *reinterpret_cast<uint2*>(ds16 + idx) = *reinterpret_cast<const uint2*>(o);
    } else if (g < 331776) {
        const int idx = (g - 327680) * 4;
        const float4 v = *reinterpret_cast<const float4*>(Dw + idx);
        u16 o[4] = { f2bf(v.x), f2bf(v.y), f2bf(v.z), f2bf(v.w) };
        *reinterpret_cast<uint2*>(dw16 + idx) = *reinterpret_cast<const uint2*>(o);
    } else if (g < 339968) {
        const int lin0 = (g - 331776) * 4;
        #pragma unroll
        for (int t = 0; t < 4; ++t) {
            const int l = lin0 + t;
            const int bb = l >> 10, rem = l & 1023, i = rem >> 5, j = rem & 31;
            // diagT[b][i][j] = Bs[32b+j, 32b+i] for j>i (weight from unit i to unit j)
            diagT[l] = (j > i) ? Bs[(size_t)(bb * 32 + j) * 1024 + (bb * 32 + i)] : 0.0f;
        }
    }
}

// ---------------- main: pipelined triangular recurrence ----------------
// 256 wgs x 320 threads. Waves 0-3: GEMM producers (2x2 tile). Wave 4: serial
// consumer with a hierarchical (8-wide sub-block) solve: short tanh chain on the
// 8x8 diagonal, latency-tolerant grouped-fma panel updates off the chain.
__global__ __launch_bounds__(320, 1) void ren_main(
    const float* __restrict__ u,
    const u16* __restrict__ bs16, const u16* __restrict__ bw16,
    const u16* __restrict__ ds16, const u16* __restrict__ dw16,
    const float* __restrict__ diagT,
    float* __restrict__ out)
{
    __shared__ __align__(16) u16   sh_S[32 * SROW];    // s history bf16 [32][1024+pad]
    __shared__ __align__(16) float sh_acc[32 * ACCW];  // pre-activation tile [32][36]
    __shared__ __align__(16) float sh_dT[2][1024];     // dbuf diag block f32 [32][32]

    const int tid  = threadIdx.x;
    const int wave = tid >> 6;
    const int lane = tid & 63;
    const int mt   = (wave >> 1) & 1;      // row-tile for GEMM waves
    const int nt   = wave & 1;             // col-tile for GEMM waves
    const int lr   = lane & 15;
    const int lk8  = (lane >> 4) << 3;
    const int row0 = blockIdx.x << 5;      // 32 batch rows per wg

    bfrag fu[4];                           // u A-frags (GEMM waves only)
    f32x4 acc;                             // next-block partial accumulator

    if (wave < 4) {
        const float* up = u + (size_t)(row0 + mt * 16 + lr) * 128 + lk8;
        #pragma unroll
        for (int kk = 0; kk < 4; ++kk) {
            float4 a = *reinterpret_cast<const float4*>(up + kk * 32);
            float4 c = *reinterpret_cast<const float4*>(up + kk * 32 + 4);
            bfrag f;
            f[0] = (short)f2bf(a.x); f[1] = (short)f2bf(a.y);
            f[2] = (short)f2bf(a.z); f[3] = (short)f2bf(a.w);
            f[4] = (short)f2bf(c.x); f[5] = (short)f2bf(c.y);
            f[6] = (short)f2bf(c.z); f[7] = (short)f2bf(c.w);
            fu[kk] = f;
        }
        if (tid < 128) {   // stage dT block 0
            const float4* g = reinterpret_cast<const float4*>(diagT);
            float4 a = g[2 * tid], c = g[2 * tid + 1];
            *reinterpret_cast<float4*>(&sh_dT[0][tid * 8])     = a;
            *reinterpret_cast<float4*>(&sh_dT[0][tid * 8 + 4]) = c;
        }
        // block 0 pre-activations = Bu only (each wave: its 16x16 quadrant)
        acc = (f32x4){0.f, 0.f, 0.f, 0.f};
        const u16* p0 = bw16 + (size_t)((nt << 4) + lr) * 128 + lk8;
        #pragma unroll
        for (int kk = 0; kk < 4; ++kk)
            acc = __builtin_amdgcn_mfma_f32_16x16x32_bf16(fu[kk], *reinterpret_cast<const bfrag*>(p0 + kk * 32), acc, 0, 0, 0);
        const int m = (mt << 4) + ((lane >> 4) << 2);
        #pragma unroll
        for (int rr = 0; rr < 4; ++rr)
            sh_acc[(m + rr) * ACCW + (nt << 4) + lr] = acc[rr];
    }
    __syncthreads();

    for (int b = 0; b < 32; ++b) {
        bfrag bfin;                        // finish B-frag, preloaded pre-barrier
        const int nb = b + 1;

        if (wave == 4) {
            // ---------- serial consumer: hierarchical solve of block b ----------
            if (lane < 32) {
                float part[32];
                const float* accr = sh_acc + lane * ACCW;
                #pragma unroll
                for (int q = 0; q < 8; ++q) {
                    float4 v = reinterpret_cast<const float4*>(accr)[q];
                    part[4*q+0] = v.x; part[4*q+1] = v.y; part[4*q+2] = v.z; part[4*q+3] = v.w;
                }
                const float4* dT4 = reinterpret_cast<const float4*>(&sh_dT[b & 1][0]);
                u16* srow = sh_S + lane * SROW + (b << 5);

                #pragma unroll
                for (int g = 0; g < 4; ++g) {
                    // (a) diagonal 8x8: preload 16 quads as one independent group
                    float4 dq0[8], dq1[8];
                    #pragma unroll
                    for (int i = 0; i < 8; ++i) {
                        dq0[i] = dT4[(8 * g + i) * 8 + 2 * g];
                        dq1[i] = dT4[(8 * g + i) * 8 + 2 * g + 1];
                    }
                    // short chain: 8 x (tanh + 8 fma); weights zero-padded for j<=i
                    float s8[8];
                    #pragma unroll
                    for (int i = 0; i < 8; ++i) {
                        float s = fast_tanh(part[8 * g + i]);
                        s8[i] = s;
                        part[8*g+0] = __builtin_fmaf(dq0[i].x, s, part[8*g+0]);
                        part[8*g+1] = __builtin_fmaf(dq0[i].y, s, part[8*g+1]);
                        part[8*g+2] = __builtin_fmaf(dq0[i].z, s, part[8*g+2]);
                        part[8*g+3] = __builtin_fmaf(dq0[i].w, s, part[8*g+3]);
                        part[8*g+4] = __builtin_fmaf(dq1[i].x, s, part[8*g+4]);
                        part[8*g+5] = __builtin_fmaf(dq1[i].y, s, part[8*g+5]);
                        part[8*g+6] = __builtin_fmaf(dq1[i].z, s, part[8*g+6]);
                        part[8*g+7] = __builtin_fmaf(dq1[i].w, s, part[8*g+7]);
                    }
                    // pack the 8 fresh s values -> sh_S (one 16B store)
                    {
                        uint4 pk;
                        u32 r0 = (__float_as_uint(s8[0]) + 0x8000u) >> 16;
                        u32 r1 = (__float_as_uint(s8[1]) + 0x8000u) >> 16;
                        u32 r2 = (__float_as_uint(s8[2]) + 0x8000u) >> 16;
                        u32 r3 = (__float_as_uint(s8[3]) + 0x8000u) >> 16;
                        u32 r4 = (__float_as_uint(s8[4]) + 0x8000u) >> 16;
                        u32 r5 = (__float_as_uint(s8[5]) + 0x8000u) >> 16;
                        u32 r6 = (__float_as_uint(s8[6]) + 0x8000u) >> 16;
                        u32 r7 = (__float_as_uint(s8[7]) + 0x8000u) >> 16;
                        pk.x = r0 | (r1 << 16);
                        pk.y = r2 | (r3 << 16);
                        pk.z = r4 | (r5 << 16);
                        pk.w = r6 | (r7 << 16);
                        *reinterpret_cast<uint4*>(srow + 8 * g) = pk;
                    }
                    // (b) panel: units 8g+8..31 += W * s8 — off-chain, 4-row chunks
                    #pragma unroll
                    for (int h = 0; h < 2; ++h) {
                        float4 pw[4][8];
                        #pragma unroll
                        for (int i = 0; i < 4; ++i)
                            #pragma unroll
                            for (int q = 2 * g + 2; q < 8; ++q)
                                pw[i][q] = dT4[(8 * g + 4 * h + i) * 8 + q];
                        #pragma unroll
                        for (int i = 0; i < 4; ++i) {
                            float s = s8[4 * h + i];
                            #pragma unroll
                            for (int q = 2 * g + 2; q < 8; ++q) {
                                float4 w = pw[i][q];
                                part[4*q+0] = __builtin_fmaf(w.x, s, part[4*q+0]);
                                part[4*q+1] = __builtin_fmaf(w.y, s, part[4*q+1]);
                                part[4*q+2] = __builtin_fmaf(w.z, s, part[4*q+2]);
                                part[4*q+3] = __builtin_fmaf(w.w, s, part[4*q+3]);
                            }
                        }
                    }
                }
            }
        } else if (b < 31) {
            // ---------- GEMM producers: partial for block b+1 (kc < b) ----------
            float4 st0, st1;
            const bool stager = (tid < 128);
            if (stager) {
                const float4* g = reinterpret_cast<const float4*>(diagT + (nb << 10));
                st0 = g[2 * tid]; st1 = g[2 * tid + 1];
            }
            const int ng = (nb << 5) + (nt << 4) + lr;     // global hid unit
            bfin = *reinterpret_cast<const bfrag*>(bs16 + (size_t)ng * 1024 + (b << 5) + lk8);

            acc = (f32x4){0.f, 0.f, 0.f, 0.f};
            const u16* p0 = bw16 + (size_t)ng * 128 + lk8;
            #pragma unroll
            for (int kk = 0; kk < 4; ++kk)
                acc = __builtin_amdgcn_mfma_f32_16x16x32_bf16(fu[kk], *reinterpret_cast<const bfrag*>(p0 + kk * 32), acc, 0, 0, 0);

            const u16* bsp = bs16 + (size_t)ng * 1024 + lk8;
            const u16* ssp = sh_S + ((mt << 4) + lr) * SROW + lk8;
            #pragma unroll 8
            for (int kc = 0; kc < b; ++kc) {
                bfrag af = *reinterpret_cast<const bfrag*>(ssp + (kc << 5));
                acc = __builtin_amdgcn_mfma_f32_16x16x32_bf16(af, *reinterpret_cast<const bfrag*>(bsp + (kc << 5)), acc, 0, 0, 0);
            }
            if (stager) {
                *reinterpret_cast<float4*>(&sh_dT[nb & 1][tid * 8])     = st0;
                *reinterpret_cast<float4*>(&sh_dT[nb & 1][tid * 8 + 4]) = st1;
            }
        }
        __syncthreads();   // s_b visible; partials done

        if (wave < 4 && b < 31) {
            // ---------- finish block b+1 with the fresh s_b k-slice ----------
            const u16* ssp = sh_S + ((mt << 4) + lr) * SROW + lk8;
            bfrag af = *reinterpret_cast<const bfrag*>(ssp + (b << 5));
            acc = __builtin_amdgcn_mfma_f32_16x16x32_bf16(af, bfin, acc, 0, 0, 0);
            const int m = (mt << 4) + ((lane >> 4) << 2);
            #pragma unroll
            for (int rr = 0; rr < 4; ++rr)
                sh_acc[(m + rr) * ACCW + (nt << 4) + lr] = acc[rr];
        }
        __syncthreads();   // sh_acc ready for serial(b+1)
    }

    if (wave >= 4) return;

    // ---------------- epilogue: y = s @ Ds^T + u @ D^T ----------------
    f32x4 ey[4];
    #pragma unroll
    for (int t = 0; t < 4; ++t) ey[t] = (f32x4){0.f, 0.f, 0.f, 0.f};

    const u16* ssp = sh_S + ((mt << 4) + lr) * SROW + lk8;
    #pragma unroll 4
    for (int kc = 0; kc < 32; ++kc) {
        bfrag af = *reinterpret_cast<const bfrag*>(ssp + (kc << 5));
        #pragma unroll
        for (int t = 0; t < 4; ++t) {
            const int n = ((nt << 2) + t) * 16 + lr;
            bfrag bf = *reinterpret_cast<const bfrag*>(ds16 + (size_t)n * 1024 + (kc << 5) + lk8);
            ey[t] = __builtin_amdgcn_mfma_f32_16x16x32_bf16(af, bf, ey[t], 0, 0, 0);
        }
    }
    #pragma unroll
    for (int kk = 0; kk < 4; ++kk) {
        #pragma unroll
        for (int t = 0; t < 4; ++t) {
            const int n = ((nt << 2) + t) * 16 + lr;
            bfrag bf = *reinterpret_cast<const bfrag*>(dw16 + n * 128 + (kk << 5) + lk8);
            ey[t] = __builtin_amdgcn_mfma_f32_16x16x32_bf16(fu[kk], bf, ey[t], 0, 0, 0);
        }
    }
    {
        const int mbase = row0 + (mt << 4) + ((lane >> 4) << 2);
        #pragma unroll
        for (int t = 0; t < 4; ++t) {
            const int n = ((nt << 2) + t) * 16 + lr;
            #pragma unroll
            for (int rr = 0; rr < 4; ++rr)
                out[(size_t)(mbase + rr) * 128 + n] = ey[t][rr];
        }
    }
}

extern "C" void kernel_launch(void* const* d_in, const int* in_sizes, int n_in,
                              void* d_out, int out_size, void* d_ws, size_t ws_size,
                              hipStream_t stream)
{
    const float* u  = (const float*)d_in[0];   // [8192,128]
    const float* Bw = (const float*)d_in[1];   // [1024,128]
    const float* Bs = (const float*)d_in[2];   // [1024,1024]
    const float* Ds = (const float*)d_in[3];   // [128,1024]
    const float* Dw = (const float*)d_in[4];   // [128,128]
    float* out = (float*)d_out;

    u16* bs16 = (u16*)d_ws;                    // 1024*1024 bf16
    u16* bw16 = bs16 + 1024 * 1024;            // 1024*128
    u16* ds16 = bw16 + 1024 * 128;             // 128*1024
    u16* dw16 = ds16 + 128 * 1024;             // 128*128
    float* diagT = (float*)(dw16 + 128 * 128); // 32 blocks x 32x32 f32, transposed

    ren_prologue<<<1328, 256, 0, stream>>>(Bs, Bw, Ds, Dw, bs16, bw16, ds16, dw16, diagT);
    ren_main<<<256, 320, 0, stream>>>(u, bs16, bw16, ds16, dw16, diagT, out);
}